// Round 1
// baseline (2496.519 us; speedup 1.0000x reference)
//
#include <hip/hip_runtime.h>

// Problem constants (L, B, S, H, F) = (16, 4, 512, 2048, 512)
#define L_DIM 16
#define B_DIM 4
#define S_DIM 512
#define H_DIM 2048
#define F_DIM 512
#define BS_DIM (B_DIM * S_DIM)          // 2048 rows per layer

#define BM 128
#define BN 128
#define BK 32
#define LDS_STRIDE (BK + 8)             // +8 bf16 = +16B: keeps 16B alignment, breaks 64B bank stride

typedef __bf16 bf16x4 __attribute__((ext_vector_type(4)));
typedef __bf16 bf16x8 __attribute__((ext_vector_type(8)));
typedef float  f32x4  __attribute__((ext_vector_type(4)));

// Stage a 128x32 fp32 tile (row-major, leading dim ld, K-offset k0) into LDS as bf16.
// G must already point at the tile's first row. 256 threads, 4 float4 loads each.
__device__ __forceinline__ void stage128x32(const float* __restrict__ G, long ld, int k0,
                                            __bf16 (*sT)[LDS_STRIDE], int tid) {
#pragma unroll
  for (int it = 0; it < 4; ++it) {
    int idx = it * 256 + tid;           // 0..1023 float4 groups
    int row = idx >> 3;                 // 8 float4 per 32-wide row
    int c4  = (idx & 7) << 2;
    float4 v = *(const float4*)(G + (long)row * ld + k0 + c4);
    bf16x4 p;
    p.x = (__bf16)v.x; p.y = (__bf16)v.y; p.z = (__bf16)v.z; p.w = (__bf16)v.w;
    *(bf16x4*)&sT[row][c4] = p;         // 8B ds_write, aligned
  }
}

// One BK=32 step: each wave does 4 A-frag + 4 B-frag ds_read_b128 and 16 MFMAs.
__device__ __forceinline__ void mma_step(const __bf16 (*sA)[LDS_STRIDE],
                                         const __bf16 (*sB)[LDS_STRIDE],
                                         f32x4 acc[4][4], int wm, int wn, int lane) {
  bf16x8 af[4], bb[4];
  const int rsel = lane & 15;
  const int koff = (lane >> 4) << 3;    // quad * 8
#pragma unroll
  for (int i = 0; i < 4; ++i)
    af[i] = *(const bf16x8*)&sA[wm + i * 16 + rsel][koff];
#pragma unroll
  for (int j = 0; j < 4; ++j)
    bb[j] = *(const bf16x8*)&sB[wn + j * 16 + rsel][koff];
#pragma unroll
  for (int i = 0; i < 4; ++i)
#pragma unroll
    for (int j = 0; j < 4; ++j)
      acc[i][j] = __builtin_amdgcn_mfma_f32_16x16x32_bf16(af[i], bb[j], acc[i][j], 0, 0, 0);
}

// feats[l] = relu(resid[l] @ enc_w[l]^T):  [2048 x 2048] @ [512 x 2048]^T -> [2048 x 512]
__global__ __launch_bounds__(256) void clt_encode(const float* __restrict__ resid,
                                                  const float* __restrict__ enc_w,
                                                  float* __restrict__ feats) {
  const int l     = blockIdx.z;
  const int m_blk = blockIdx.x * BM;    // over BS_DIM = 2048
  const int n_blk = blockIdx.y * BN;    // over F_DIM  = 512
  const float* A  = resid + (long)l * BS_DIM * H_DIM + (long)m_blk * H_DIM;
  const float* Bm = enc_w + (long)l * F_DIM * H_DIM + (long)n_blk * H_DIM;
  float* C        = feats + (long)l * BS_DIM * F_DIM;

  __shared__ __bf16 sA[BM][LDS_STRIDE];
  __shared__ __bf16 sB[BN][LDS_STRIDE];

  const int tid  = threadIdx.x;
  const int lane = tid & 63;
  const int wave = tid >> 6;
  const int wm   = (wave >> 1) * 64;
  const int wn   = (wave & 1) * 64;

  f32x4 acc[4][4];
  const f32x4 zero = {0.f, 0.f, 0.f, 0.f};
#pragma unroll
  for (int i = 0; i < 4; ++i)
#pragma unroll
    for (int j = 0; j < 4; ++j) acc[i][j] = zero;

  for (int k0 = 0; k0 < H_DIM; k0 += BK) {
    stage128x32(A, H_DIM, k0, sA, tid);
    stage128x32(Bm, H_DIM, k0, sB, tid);
    __syncthreads();
    mma_step(sA, sB, acc, wm, wn, lane);
    __syncthreads();
  }

  // Epilogue: C/D layout col = lane&15, row = (lane>>4)*4 + r.  ReLU.
  const int rsel = lane & 15;
  const int rbase = (lane >> 4) * 4;
#pragma unroll
  for (int i = 0; i < 4; ++i)
#pragma unroll
    for (int j = 0; j < 4; ++j)
#pragma unroll
      for (int r = 0; r < 4; ++r) {
        int m = m_blk + wm + i * 16 + rbase + r;
        int n = n_blk + wn + j * 16 + rsel;
        float v = acc[i][j][r];
        C[(long)m * F_DIM + n] = v > 0.f ? v : 0.f;
      }
}

// recon[t] = sum_{s<=t} feats[s] @ dec_w[s,t]^T : [2048x512] @ [2048x512]^T -> [2048x2048]
__global__ __launch_bounds__(256) void clt_decode(const float* __restrict__ feats,
                                                  const float* __restrict__ dec_w,
                                                  float* __restrict__ recon) {
  const int t     = (L_DIM - 1) - blockIdx.z;   // heavy targets launch first
  const int m_blk = blockIdx.x * BM;            // over BS_DIM = 2048
  const int n_blk = blockIdx.y * BN;            // over H_DIM  = 2048
  float* C        = recon + (long)t * BS_DIM * H_DIM;

  __shared__ __bf16 sA[BM][LDS_STRIDE];
  __shared__ __bf16 sB[BN][LDS_STRIDE];

  const int tid  = threadIdx.x;
  const int lane = tid & 63;
  const int wave = tid >> 6;
  const int wm   = (wave >> 1) * 64;
  const int wn   = (wave & 1) * 64;

  f32x4 acc[4][4];
  const f32x4 zero = {0.f, 0.f, 0.f, 0.f};
#pragma unroll
  for (int i = 0; i < 4; ++i)
#pragma unroll
    for (int j = 0; j < 4; ++j) acc[i][j] = zero;

  for (int s = 0; s <= t; ++s) {
    const float* A  = feats + (long)s * BS_DIM * F_DIM + (long)m_blk * F_DIM;
    const float* Bm = dec_w + ((long)s * L_DIM + t) * (long)H_DIM * F_DIM
                            + (long)n_blk * F_DIM;
    for (int k0 = 0; k0 < F_DIM; k0 += BK) {
      stage128x32(A, F_DIM, k0, sA, tid);
      stage128x32(Bm, F_DIM, k0, sB, tid);
      __syncthreads();
      mma_step(sA, sB, acc, wm, wn, lane);
      __syncthreads();
    }
  }

  const int rsel = lane & 15;
  const int rbase = (lane >> 4) * 4;
#pragma unroll
  for (int i = 0; i < 4; ++i)
#pragma unroll
    for (int j = 0; j < 4; ++j)
#pragma unroll
      for (int r = 0; r < 4; ++r) {
        int m = m_blk + wm + i * 16 + rbase + r;
        int n = n_blk + wn + j * 16 + rsel;
        C[(long)m * H_DIM + n] = acc[i][j][r];
      }
}

extern "C" void kernel_launch(void* const* d_in, const int* in_sizes, int n_in,
                              void* d_out, int out_size, void* d_ws, size_t ws_size,
                              hipStream_t stream) {
  const float* resid = (const float*)d_in[0];   // [L, B, S, H] fp32
  const float* enc_w = (const float*)d_in[1];   // [L, F, H]    fp32
  const float* dec_w = (const float*)d_in[2];   // [L, L, H, F] fp32

  float* out   = (float*)d_out;
  float* feats = out;                                   // [L, B, S, F] = 16,777,216 floats
  float* recon = out + (long)L_DIM * BS_DIM * F_DIM;    // [L, B, S, H]

  dim3 blk(256);
  // Encode: M=2048 (16 tiles), N=512 (4 tiles), one z per layer.
  clt_encode<<<dim3(BS_DIM / BM, F_DIM / BN, L_DIM), blk, 0, stream>>>(resid, enc_w, feats);
  // Decode: M=2048 (16), N=2048 (16), one z per target layer (reads feats fp32 from d_out).
  clt_decode<<<dim3(BS_DIM / BM, H_DIM / BN, L_DIM), blk, 0, stream>>>(feats, dec_w, recon);
}